// Round 1
// baseline (9219.285 us; speedup 1.0000x reference)
//
#include <hip/hip_runtime.h>

#define B_ 256
#define T_ 512
#define I_ 512
#define H_ 1024
#define O_ 128
#define BT_ (B_*T_)

typedef short s16x8 __attribute__((ext_vector_type(8)));
typedef float f32x4 __attribute__((ext_vector_type(4)));

#define MFMA16(a,b,c) __builtin_amdgcn_mfma_f32_16x16x32_bf16(a, b, c, 0, 0, 0)

__device__ __forceinline__ short f2bf(float x){
  unsigned u = __float_as_uint(x);
  u = u + 0x7FFFu + ((u >> 16) & 1u);
  return (short)(u >> 16);
}
__device__ __forceinline__ float bf2f(short h){
  return __uint_as_float(((unsigned)(unsigned short)h) << 16);
}

// Convert 16 consecutive fp32 -> 16 bf16 and store to LDS (two 16B stores).
__device__ __forceinline__ void stage16(const float* __restrict__ src, short* dst){
  float4 v0 = *(const float4*)(src + 0);
  float4 v1 = *(const float4*)(src + 4);
  float4 v2 = *(const float4*)(src + 8);
  float4 v3 = *(const float4*)(src + 12);
  s16x8 t0 = { f2bf(v0.x), f2bf(v0.y), f2bf(v0.z), f2bf(v0.w),
               f2bf(v1.x), f2bf(v1.y), f2bf(v1.z), f2bf(v1.w) };
  s16x8 t1 = { f2bf(v2.x), f2bf(v2.y), f2bf(v2.z), f2bf(v2.w),
               f2bf(v3.x), f2bf(v3.y), f2bf(v3.z), f2bf(v3.w) };
  *(s16x8*)(dst)     = t0;
  *(s16x8*)(dst + 8) = t1;
}

// Copy 16 bf16 global->LDS
__device__ __forceinline__ void copy16(const short* __restrict__ src, short* dst){
  *(s16x8*)(dst)     = *(const s16x8*)(src);
  *(s16x8*)(dst + 8) = *(const s16x8*)(src + 8);
}

// ---------------- prep: split W_h (fp32) into bf16 hi/lo planes ----------------
__global__ __launch_bounds__(256) void prep_split_W(const float* __restrict__ W,
                                                    short* __restrict__ Whi,
                                                    short* __restrict__ Wlo, int n){
  int i = blockIdx.x * 256 + threadIdx.x;
  if (i < n){
    float w = W[i];
    short hi = f2bf(w);
    float lo = w - bf2f(hi);
    Whi[i] = hi; Wlo[i] = f2bf(lo);
  }
}

// ---------------- phase 1: xw = x @ W_in^T + b_in  ->  hid (in place of hidden_all) ----
// M = BT_ (131072), N = H_ (1024), K = I_ (512). Tile 128x128, BK=32, 4 waves (2x2).
__global__ __launch_bounds__(256) void gemm_xw(const float* __restrict__ A,
                                               const float* __restrict__ Wn,
                                               const float* __restrict__ bias,
                                               float* __restrict__ out){
  __shared__ __align__(16) short As[128][40];
  __shared__ __align__(16) short Bs[128][40];
  int bm = blockIdx.x, bn = blockIdx.y;
  int tid = threadIdx.x;
  int lane = tid & 63, wave = tid >> 6;
  int wm = wave >> 1, wn = wave & 1;
  int row0 = bm * 128, col0 = bn * 128;

  f32x4 acc[4][4] = {};

  int sr = tid >> 1, ss = (tid & 1) * 16;  // staging: row, 16-col segment

  for (int k0 = 0; k0 < I_; k0 += 32){
    stage16(A  + (size_t)(row0 + sr) * I_ + k0 + ss, &As[sr][ss]);
    stage16(Wn + (size_t)(col0 + sr) * I_ + k0 + ss, &Bs[sr][ss]);
    __syncthreads();

    int rsel = lane & 15, ko = (lane >> 4) * 8;
    s16x8 af[4], bf[4];
    #pragma unroll
    for (int f = 0; f < 4; ++f){
      af[f] = *(const s16x8*)&As[wm*64 + f*16 + rsel][ko];
      bf[f] = *(const s16x8*)&Bs[wn*64 + f*16 + rsel][ko];
    }
    #pragma unroll
    for (int fm = 0; fm < 4; ++fm)
      #pragma unroll
      for (int fn = 0; fn < 4; ++fn)
        acc[fm][fn] = MFMA16(af[fm], bf[fn], acc[fm][fn]);
    __syncthreads();
  }

  int rbase = (lane >> 4) * 4, cbase = lane & 15;
  #pragma unroll
  for (int fm = 0; fm < 4; ++fm)
    #pragma unroll
    for (int fn = 0; fn < 4; ++fn){
      int gcol = col0 + wn*64 + fn*16 + cbase;
      float b = bias[gcol];
      #pragma unroll
      for (int r = 0; r < 4; ++r){
        int grow = row0 + wm*64 + fm*16 + rbase + r;
        out[(size_t)grow * H_ + gcol] = acc[fm][fn][r] + b;
      }
    }
}

// ---------------- phase 2: one recurrence step ----------------
// h_t = relu(xw_t + h_{t-1} @ W_h^T + b_h); split-bf16 3-product GEMM.
// Tile 32x64, BK=64, grid (8,16), 4 waves (2x2), wave tile 16x32 (2 N-frags).
__global__ __launch_bounds__(256) void rnn_step(float* __restrict__ hid,
                                                const short* __restrict__ Whi,
                                                const short* __restrict__ Wlo,
                                                short* __restrict__ planes,
                                                const float* __restrict__ bh,
                                                int t){
  __shared__ __align__(16) short Ahi[32][72];
  __shared__ __align__(16) short Alo[32][72];
  __shared__ __align__(16) short Bhi[64][72];
  __shared__ __align__(16) short Blo[64][72];

  int bm = blockIdx.x, bn = blockIdx.y;     // 8 x 16
  int tid = threadIdx.x;
  int lane = tid & 63, wave = tid >> 6;
  int wm = wave >> 1, wn = wave & 1;
  int row0 = bm * 32, col0 = bn * 64;

  const int PLANE = B_ * H_;                 // 262144 shorts
  int s_in  = t & 1;
  int s_out = (t + 1) & 1;
  const short* inHi = planes + (size_t)s_in * 2 * PLANE;
  const short* inLo = inHi + PLANE;
  short* outHi = planes + (size_t)s_out * 2 * PLANE;
  short* outLo = outHi + PLANE;

  f32x4 acc[2] = {};

  if (t > 0){
    // staging roles
    int ap = tid >> 7;                       // 0: hi, 1: lo   (A planes)
    int ar = (tid & 127) >> 2;               // 32 rows
    int as = (tid & 3) * 16;                 // 4 segs of 16
    const short* aSrcBase = ap ? inLo : inHi;
    short* aDst = ap ? &Alo[ar][as] : &Ahi[ar][as];

    int br = (tid & 127) >> 1;               // 64 rows
    int bs = (tid & 1) * 32;                 // 2 segs of 32
    const short* bSrcBase = ap ? Wlo : Whi;

    int rsel = lane & 15;

    for (int k0 = 0; k0 < H_; k0 += 64){
      copy16(aSrcBase + (size_t)(row0 + ar) * H_ + k0 + as, aDst);
      {
        const short* bsrc = bSrcBase + (size_t)(col0 + br) * H_ + k0 + bs;
        short* bdst = ap ? &Blo[br][bs] : &Bhi[br][bs];
        copy16(bsrc, bdst);
        copy16(bsrc + 16, bdst + 16);
      }
      __syncthreads();

      #pragma unroll
      for (int kk = 0; kk < 64; kk += 32){
        int ko = kk + (lane >> 4) * 8;
        s16x8 ah = *(const s16x8*)&Ahi[wm*16 + rsel][ko];
        s16x8 al = *(const s16x8*)&Alo[wm*16 + rsel][ko];
        #pragma unroll
        for (int fn = 0; fn < 2; ++fn){
          s16x8 bh16 = *(const s16x8*)&Bhi[wn*32 + fn*16 + rsel][ko];
          s16x8 bl16 = *(const s16x8*)&Blo[wn*32 + fn*16 + rsel][ko];
          acc[fn] = MFMA16(ah, bh16, acc[fn]);
          acc[fn] = MFMA16(ah, bl16, acc[fn]);
          acc[fn] = MFMA16(al, bh16, acc[fn]);
        }
      }
      __syncthreads();
    }
  }

  int rbase = (lane >> 4) * 4, cbase = lane & 15;
  #pragma unroll
  for (int fn = 0; fn < 2; ++fn){
    int gcol = col0 + wn*32 + fn*16 + cbase;
    float bias = bh[gcol];
    #pragma unroll
    for (int r = 0; r < 4; ++r){
      int b = row0 + wm*16 + rbase + r;             // batch index
      size_t idx = ((size_t)b * T_ + t) * H_ + gcol;
      float v = acc[fn][r] + hid[idx] + bias;
      v = v > 0.0f ? v : 0.0f;
      hid[idx] = v;
      short hi = f2bf(v);
      float lo = v - bf2f(hi);
      outHi[(size_t)b * H_ + gcol] = hi;
      outLo[(size_t)b * H_ + gcol] = f2bf(lo);
    }
  }
}

// ---------------- phase 3: out = hidden @ W_o^T + b_o ----------------
// M = BT_, N = O_ (128), K = H_ (1024). Tile 128x128 (one N tile), BK=32.
__global__ __launch_bounds__(256) void gemm_out(const float* __restrict__ A,
                                                const float* __restrict__ Wo,
                                                const float* __restrict__ bias,
                                                float* __restrict__ out){
  __shared__ __align__(16) short As[128][40];
  __shared__ __align__(16) short Bs[128][40];
  int bm = blockIdx.x;
  int tid = threadIdx.x;
  int lane = tid & 63, wave = tid >> 6;
  int wm = wave >> 1, wn = wave & 1;
  int row0 = bm * 128;

  f32x4 acc[4][4] = {};
  int sr = tid >> 1, ss = (tid & 1) * 16;

  for (int k0 = 0; k0 < H_; k0 += 32){
    stage16(A  + (size_t)(row0 + sr) * H_ + k0 + ss, &As[sr][ss]);
    stage16(Wo + (size_t)sr * H_ + k0 + ss, &Bs[sr][ss]);
    __syncthreads();

    int rsel = lane & 15, ko = (lane >> 4) * 8;
    s16x8 af[4], bf[4];
    #pragma unroll
    for (int f = 0; f < 4; ++f){
      af[f] = *(const s16x8*)&As[wm*64 + f*16 + rsel][ko];
      bf[f] = *(const s16x8*)&Bs[wn*64 + f*16 + rsel][ko];
    }
    #pragma unroll
    for (int fm = 0; fm < 4; ++fm)
      #pragma unroll
      for (int fn = 0; fn < 4; ++fn)
        acc[fm][fn] = MFMA16(af[fm], bf[fn], acc[fm][fn]);
    __syncthreads();
  }

  int rbase = (lane >> 4) * 4, cbase = lane & 15;
  #pragma unroll
  for (int fm = 0; fm < 4; ++fm)
    #pragma unroll
    for (int fn = 0; fn < 4; ++fn){
      int gcol = wn*64 + fn*16 + cbase;      // 0..127
      float b = bias[gcol];
      #pragma unroll
      for (int r = 0; r < 4; ++r){
        int grow = row0 + wm*64 + fm*16 + rbase + r;
        out[(size_t)grow * O_ + gcol] = acc[fm][fn][r] + b;
      }
    }
}

extern "C" void kernel_launch(void* const* d_in, const int* in_sizes, int n_in,
                              void* d_out, int out_size, void* d_ws, size_t ws_size,
                              hipStream_t stream) {
  const float* x    = (const float*)d_in[0];
  const float* W_in = (const float*)d_in[1];
  const float* b_in = (const float*)d_in[2];
  const float* W_h  = (const float*)d_in[3];
  const float* b_h  = (const float*)d_in[4];
  const float* W_o  = (const float*)d_in[5];
  const float* b_o  = (const float*)d_in[6];

  float* out = (float*)d_out;
  float* hid = out + (size_t)BT_ * O_;   // hidden_all region (B,T,H)

  // Scratch stashed in the (B,T,O) output region (64 MB), overwritten by phase 3.
  short* Whi    = (short*)d_out;                       // 1024*1024
  short* Wlo    = Whi + (size_t)H_ * H_;               // 1024*1024
  short* planes = Wlo + (size_t)H_ * H_;               // 2 slots x (hi+lo) x 256*1024

  prep_split_W<<<dim3((H_*H_ + 255)/256), 256, 0, stream>>>(W_h, Whi, Wlo, H_*H_);

  gemm_xw<<<dim3(BT_/128, H_/128), 256, 0, stream>>>(x, W_in, b_in, hid);

  for (int t = 0; t < T_; ++t)
    rnn_step<<<dim3(B_/32, H_/64), 256, 0, stream>>>(hid, Whi, Wlo, planes, b_h, t);

  gemm_out<<<dim3(BT_/128), 256, 0, stream>>>(hid, W_o, b_o, out);
}